// Round 6
// baseline (309.478 us; speedup 1.0000x reference)
//
#include <hip/hip_runtime.h>

typedef __bf16 bf16x8 __attribute__((ext_vector_type(8)));
typedef __bf16 bf16x4v __attribute__((ext_vector_type(4)));
typedef float f32x4 __attribute__((ext_vector_type(4)));

#define LDS_ASYNC16(g, l)                                            \
  __builtin_amdgcn_global_load_lds(                                  \
      (__attribute__((address_space(1))) void*)(g),                  \
      (__attribute__((address_space(3))) void*)(l), 16, 0, 0)

#define MFMA16(a, b, c) __builtin_amdgcn_mfma_f32_16x16x32_bf16(a, b, c, 0, 0, 0)

#if __has_builtin(__builtin_amdgcn_exp2f)
#define EXP2F(x) __builtin_amdgcn_exp2f(x)
#else
#define EXP2F(x) exp2f(x)
#endif

// log2(e)/8 and -log2(e)/16: scores computed directly in log2 domain.
#define QSCALE 0.18033688011112042f
#define KBIAS -0.09016844005556021f
#define LN1E4_32 0.28782313662425572f  // ln(10000)/32

// ---------------------------------------------------------------------------
// prep: batched weight transpose+cast (gy<80) and x fp32->bf16 cast (gy>=80).
// grid (32, 112), 256 threads.
__global__ void prep_kernel(const float* __restrict__ x,
                            const float* __restrict__ Wq,
                            const float* __restrict__ Wk,
                            const float* __restrict__ Wv,
                            const float* __restrict__ Wo,
                            __bf16* __restrict__ xb, __bf16* __restrict__ W1T,
                            __bf16* __restrict__ WoT) {
  int gy = blockIdx.y;
  if (gy >= 80) {
    // cast 2097152 float4s over 1024 blocks -> 8 float4/thread, strided
    int bid = (gy - 80) * 32 + blockIdx.x;
    int base = bid * 2048 + threadIdx.x;
#pragma unroll
    for (int u = 0; u < 8; ++u) {
      int i = base + u * 256;
      float4 v = ((const float4*)x)[i];
      bf16x4v o;
      o[0] = (__bf16)v.x; o[1] = (__bf16)v.y;
      o[2] = (__bf16)v.z; o[3] = (__bf16)v.w;
      ((bf16x4v*)xb)[i] = o;
    }
    return;
  }
  __shared__ float tile[64][65];
  const float* src;
  int srcld, n0;
  __bf16* dst;
  if (gy < 32) {
    src = Wq; srcld = 2048; dst = W1T; n0 = gy * 64;
  } else if (gy < 40) {
    src = Wk; srcld = 512; dst = W1T + (size_t)2048 * 2048; n0 = (gy - 32) * 64;
  } else if (gy < 48) {
    src = Wv; srcld = 512; dst = W1T + (size_t)2560 * 2048; n0 = (gy - 40) * 64;
  } else {
    src = Wo; srcld = 2048; dst = WoT; n0 = (gy - 48) * 64;
  }
  int k0 = blockIdx.x * 64;
  int tl = threadIdx.x >> 6, c = threadIdx.x & 63;
#pragma unroll
  for (int rr = 0; rr < 16; ++rr) {
    int k = rr * 4 + tl;
    tile[k][c] = src[(size_t)(k0 + k) * srcld + n0 + c];
  }
  __syncthreads();
#pragma unroll
  for (int rr = 0; rr < 16; ++rr) {
    int n = rr * 4 + tl;
    dst[(size_t)(n0 + n) * 2048 + k0 + c] = (__bf16)tile[c][n];
  }
}

// ---------------------------------------------------------------------------
// Software-pipelined K-loop (attn-proven structure): double-buffered LDS,
// raw s_barrier + manual s_waitcnt vmcnt(4) so the next tile's
// global_load_lds batch stays in flight across the whole compute phase.
#define GEMM_PIPELINE_LOOP(KDIM)                                              \
  {                                                                           \
    /* prologue: tile 0 -> buf 0 */                                           \
    LDS_ASYNC16(gA, As + wave * 512);                                         \
    LDS_ASYNC16(gA + stepA, As + 2048 + wave * 512);                          \
    LDS_ASYNC16(gB, Bs + wave * 512);                                         \
    LDS_ASYNC16(gB + stepA, Bs + 2048 + wave * 512);                          \
    gA += 32;                                                                 \
    gB += 32;                                                                 \
    for (int k0 = 0; k0 < (KDIM); k0 += 32) {                                 \
      int cur = (k0 >> 5) & 1;                                                \
      if (k0 + 32 < (KDIM)) {                                                 \
        __bf16* dA = As + (cur ^ 1) * 4096 + wave * 512;                      \
        __bf16* dB = Bs + (cur ^ 1) * 4096 + wave * 512;                      \
        LDS_ASYNC16(gA, dA);                                                  \
        LDS_ASYNC16(gA + stepA, dA + 2048);                                   \
        LDS_ASYNC16(gB, dB);                                                  \
        LDS_ASYNC16(gB + stepA, dB + 2048);                                   \
        gA += 32;                                                             \
        gB += 32;                                                             \
        asm volatile("s_waitcnt vmcnt(4)" ::: "memory");                      \
      } else {                                                                \
        asm volatile("s_waitcnt vmcnt(0)" ::: "memory");                      \
      }                                                                       \
      __builtin_amdgcn_s_barrier();                                           \
      const __bf16* Ac = As + cur * 4096;                                     \
      const __bf16* Bc = Bs + cur * 4096;                                     \
      bf16x8 af[4], bfr[4];                                                   \
      _Pragma("unroll") for (int mt = 0; mt < 4; ++mt) af[mt] =               \
          *(const bf16x8*)(Ac + (wm + mt * 16 + l16) * 32 + quad * 8);        \
      _Pragma("unroll") for (int nt = 0; nt < 4; ++nt) bfr[nt] =              \
          *(const bf16x8*)(Bc + (wn + nt * 16 + l16) * 32 + quad * 8);        \
      _Pragma("unroll") for (int mt = 0; mt < 4; ++mt)                        \
          _Pragma("unroll") for (int nt = 0; nt < 4; ++nt) acc[mt][nt] =      \
              MFMA16(af[mt], bfr[nt], acc[mt][nt]);                           \
      __builtin_amdgcn_s_barrier();                                           \
    }                                                                         \
  }

// ---------------------------------------------------------------------------
// pipelined bf16 GEMM: C(MxN) = A(MxK) * B^T, B (N x K) row-major.
template <int OUTBF16>
__global__ __launch_bounds__(256) void gemm_bt(const __bf16* __restrict__ A,
                                               const __bf16* __restrict__ B,
                                               void* __restrict__ Cout, int M,
                                               int N, int K) {
  __shared__ __bf16 As[2 * 128 * 32];
  __shared__ __bf16 Bs[2 * 128 * 32];
  int tid = threadIdx.x;
  int wave = tid >> 6, lane = tid & 63;
  int quad = lane >> 4, l16 = lane & 15;
  int wm = (wave & 1) * 64, wn = (wave >> 1) * 64;
  int tm = blockIdx.y * 128, tn = blockIdx.x * 128;

  f32x4 acc[4][4] = {};

  int srow = tid >> 2;
  int scol = (tid & 3) * 8;
  const __bf16* gA = A + (size_t)(tm + srow) * K + scol;
  const __bf16* gB = B + (size_t)(tn + srow) * K + scol;
  size_t stepA = (size_t)64 * K;

  GEMM_PIPELINE_LOOP(K);

  int r0 = tm + wm + quad * 4;
  int c0 = tn + wn + l16;
#pragma unroll
  for (int mt = 0; mt < 4; ++mt)
#pragma unroll
    for (int nt = 0; nt < 4; ++nt)
#pragma unroll
      for (int r = 0; r < 4; ++r) {
        size_t idx = (size_t)(r0 + mt * 16 + r) * N + (c0 + nt * 16);
        if (OUTBF16)
          ((__bf16*)Cout)[idx] = (__bf16)acc[mt][nt][r];
        else
          ((float*)Cout)[idx] = acc[mt][nt][r];
      }
}

// ---------------------------------------------------------------------------
// QKV GEMM (pipelined) with fused RoPE / conformal-bias / V-transpose
// epilogue. Each wave's 64-col span is one head; RoPE partner of col i
// (i+32) is in the SAME lane (nt vs nt+2) -> in-register rotation.
// blockIdx.x: 0..15 -> Q (RoPE, *log2e/8), 16..19 -> K (RoPE + bias),
// 20..23 -> V (direct transposed store to VT).
__global__ __launch_bounds__(256) void gemm_qkv(
    const __bf16* __restrict__ A, const __bf16* __restrict__ B,
    __bf16* __restrict__ Qr, __bf16* __restrict__ Kr, __bf16* __restrict__ VT,
    float* __restrict__ bias2) {
  const int K = 2048;
  __shared__ __bf16 As[2 * 128 * 32];
  __shared__ __bf16 Bs[2 * 128 * 32];
  int tid = threadIdx.x;
  int wave = tid >> 6, lane = tid & 63;
  int quad = lane >> 4, l16 = lane & 15;
  int wm = (wave & 1) * 64, wn = (wave >> 1) * 64;
  int tm = blockIdx.y * 128, tn = blockIdx.x * 128;

  f32x4 acc[4][4] = {};

  int srow = tid >> 2;
  int scol = (tid & 3) * 8;
  const __bf16* gA = A + (size_t)(tm + srow) * K + scol;
  const __bf16* gB = B + (size_t)(tn + srow) * K + scol;
  size_t stepA = (size_t)64 * K;

  GEMM_PIPELINE_LOOP(K);

  int r0 = tm + wm + quad * 4;  // global row = b*1024 + t
  int c0 = tn + wn;             // 64-aligned: one head per wave

  if (blockIdx.x < 20) {
    bool isQ = (blockIdx.x < 16);
    float invf0 = expf((float)l16 * -LN1E4_32);
    float invf1 = expf((float)(l16 + 16) * -LN1E4_32);
    int h = isQ ? (c0 >> 6) : ((c0 - 2048) >> 6);
    __bf16* base = isQ ? Qr : Kr;
    int nh = isQ ? 32 : 8;
#pragma unroll
    for (int mt = 0; mt < 4; ++mt) {
      float nsq[4];
#pragma unroll
      for (int r = 0; r < 4; ++r) {
        int row = r0 + mt * 16 + r;
        int t = row & 1023, b = row >> 10;
        float tf = (float)t;
        float a0 = tf * invf0, a1 = tf * invf1;
        float s0, c0f, s1, c1f;
        sincosf(a0, &s0, &c0f);
        sincosf(a1, &s1, &c1f);
        float oa = acc[mt][0][r] * c0f - acc[mt][2][r] * s0;  // d = l16
        float oc = acc[mt][2][r] * c0f + acc[mt][0][r] * s0;  // d = 32+l16
        float ob = acc[mt][1][r] * c1f - acc[mt][3][r] * s1;  // d = 16+l16
        float od = acc[mt][3][r] * c1f + acc[mt][1][r] * s1;  // d = 48+l16
        if (isQ) {
          oa *= QSCALE; ob *= QSCALE; oc *= QSCALE; od *= QSCALE;
        }
        __bf16 ba = (__bf16)oa, bb = (__bf16)ob, bc = (__bf16)oc,
               bd = (__bf16)od;
        __bf16* dst = base + (((size_t)b * nh + h) * 1024 + t) * 64;
        dst[l16] = ba;
        dst[16 + l16] = bb;
        dst[32 + l16] = bc;
        dst[48 + l16] = bd;
        float fa = (float)ba, fb = (float)bb, fc = (float)bc, fd = (float)bd;
        nsq[r] = fa * fa + fb * fb + fc * fc + fd * fd;
      }
      if (!isQ) {
#pragma unroll
        for (int r = 0; r < 4; ++r) {
          float nl = nsq[r];
          nl += __shfl_xor(nl, 1);
          nl += __shfl_xor(nl, 2);
          nl += __shfl_xor(nl, 4);
          nl += __shfl_xor(nl, 8);
          if (l16 == 0) {
            int row = r0 + mt * 16 + r;
            int t = row & 1023, b = row >> 10;
            bias2[((size_t)b * 8 + h) * 1024 + t] = KBIAS * nl;
          }
        }
      }
    }
  } else {
    int kvh = (c0 - 2560) >> 6;
#pragma unroll
    for (int mt = 0; mt < 4; ++mt) {
      int rowb = r0 + mt * 16;
      int t = rowb & 1023, b = rowb >> 10;
#pragma unroll
      for (int nt = 0; nt < 4; ++nt) {
        int d = nt * 16 + l16;
        bf16x4v ov;
#pragma unroll
        for (int r = 0; r < 4; ++r) ov[r] = (__bf16)acc[mt][nt][r];
        *(bf16x4v*)(VT + ((size_t)(b * 8 + kvh) * 64 + d) * 1024 + t) = ov;
      }
    }
  }
}

// ---------------------------------------------------------------------------
// Flash attention, conformal scores, no online max (scores bounded), S^T and
// O^T formulations, software-pipelined K/V staging (raw s_barrier + manual
// s_waitcnt vmcnt(8): next tile's global_load_lds stays in flight).
// grid: (32 heads, 8 qtiles reversed, 4 batch), 256 threads.
__global__ __launch_bounds__(256, 2) void attn_kernel(
    const __bf16* __restrict__ Q, const __bf16* __restrict__ Kc,
    const __bf16* __restrict__ VT, const float* __restrict__ bias2,
    __bf16* __restrict__ Y) {
  const int T = 1024;
  int h = blockIdx.x, qt = 7 - blockIdx.y, b = blockIdx.z;
  int kv = h >> 2;
  int tid = threadIdx.x;
  int wave = tid >> 6, lane = tid & 63;
  int quad = lane >> 4, l16 = lane & 15;

  __shared__ __bf16 KsA[2][8 * 128 * 8];  // 2 x 16KB [d-chunk][key][8]
  __shared__ __bf16 VsA[2][16 * 64 * 8];  // 2 x 16KB [key-chunk][d][8]
  __shared__ __bf16 Ps[4][8 * 32 * 8];    // 16KB: 4KB/wave [cp][qslot][8]

  const __bf16* Qb = Q + (((size_t)b * 32 + h) * T + qt * 128 + wave * 32) * 64;
  const __bf16* Kb = Kc + ((size_t)b * 8 + kv) * T * 64;
  const __bf16* Vb = VT + ((size_t)b * 8 + kv) * 64 * T;
  const float* nb = bias2 + ((size_t)b * 8 + kv) * T;
  __bf16* Pw = &Ps[wave][0];

  bf16x8 qf[2][2];
#pragma unroll
  for (int nt = 0; nt < 2; ++nt)
#pragma unroll
    for (int kd = 0; kd < 2; ++kd)
      qf[nt][kd] =
          *(const bf16x8*)(Qb + (size_t)(nt * 16 + l16) * 64 + kd * 32 + quad * 8);

  bf16x8 onesf;
#pragma unroll
  for (int u = 0; u < 8; ++u) onesf[u] = (__bf16)1.0f;

  f32x4 oacc[2][4] = {};
  f32x4 lacc[2] = {};

#define STAGE_TILE(k0_, buf_)                                                 \
  {                                                                           \
    _Pragma("unroll") for (int u = 0; u < 8; ++u) {                           \
      int t = wave * 8 + u;                                                   \
      if (t < 16) {                                                           \
        int c = t >> 1, kh = t & 1;                                           \
        LDS_ASYNC16(                                                          \
            Kb + (size_t)((k0_) + kh * 64) * 64 + c * 8 + (size_t)lane * 64,  \
            KsA[buf_] + c * 1024 + kh * 512);                                 \
      } else {                                                                \
        int c = t - 16;                                                       \
        LDS_ASYNC16(Vb + (size_t)lane * T + (k0_) + c * 8,                    \
                    VsA[buf_] + c * 512);                                     \
      }                                                                       \
    }                                                                         \
  }

  STAGE_TILE(0, 0);

  for (int j = 0; j <= qt; ++j) {
    int k0 = j * 128;
    int cur = j & 1;
    bool diag = (j == qt);

    f32x4 bv[8];
#pragma unroll
    for (int mt = 0; mt < 8; ++mt)
      bv[mt] = *(const f32x4*)(nb + k0 + mt * 16 + quad * 4);

    if (j < qt) {
      STAGE_TILE(k0 + 128, cur ^ 1);
      asm volatile("s_waitcnt vmcnt(8)" ::: "memory");
    } else {
      asm volatile("s_waitcnt vmcnt(0)" ::: "memory");
    }
    __builtin_amdgcn_s_barrier();

    const __bf16* Ksc = KsA[cur];
    const __bf16* Vsc = VsA[cur];

    f32x4 sacc[8][2];
#pragma unroll
    for (int mt = 0; mt < 8; ++mt) {
      sacc[mt][0] = bv[mt];
      sacc[mt][1] = bv[mt];
    }
#pragma unroll
    for (int kd = 0; kd < 2; ++kd)
#pragma unroll
      for (int mt = 0; mt < 8; ++mt) {
        bf16x8 kf =
            *(const bf16x8*)(Ksc + (kd * 4 + quad) * 1024 + (mt * 16 + l16) * 8);
        sacc[mt][0] = MFMA16(kf, qf[0][kd], sacc[mt][0]);
        sacc[mt][1] = MFMA16(kf, qf[1][kd], sacc[mt][1]);
      }

    if (diag) {
#pragma unroll
      for (int mt = 0; mt < 8; ++mt)
#pragma unroll
        for (int nt = 0; nt < 2; ++nt)
#pragma unroll
          for (int r = 0; r < 4; ++r) {
            int key = mt * 16 + quad * 4 + r;
            int ql = wave * 32 + nt * 16 + l16;
            if (key > ql) sacc[mt][nt][r] = -1e30f;
          }
    }

#pragma unroll
    for (int kh = 0; kh < 2; ++kh) {
#pragma unroll
      for (int mh = 0; mh < 4; ++mh) {
        int mt = 4 * kh + mh;
        int cp = 2 * mh + (quad >> 1);
        int halfo = (quad & 1) * 4;
#pragma unroll
        for (int nt = 0; nt < 2; ++nt) {
          bf16x4v pk;
#pragma unroll
          for (int r = 0; r < 4; ++r) pk[r] = (__bf16)EXP2F(sacc[mt][nt][r]);
          int qs = ((nt * 16 + l16) + 2 * cp) & 31;
          *(bf16x4v*)(Pw + cp * 256 + qs * 8 + halfo) = pk;
        }
      }
#pragma unroll
      for (int kil = 0; kil < 2; ++kil) {
        int cp = 4 * kil + quad;
        bf16x8 pf0 = *(const bf16x8*)(Pw + cp * 256 + ((l16 + 2 * cp) & 31) * 8);
        bf16x8 pf1 =
            *(const bf16x8*)(Pw + cp * 256 + ((16 + l16 + 2 * cp) & 31) * 8);
        lacc[0] = MFMA16(onesf, pf0, lacc[0]);
        lacc[1] = MFMA16(onesf, pf1, lacc[1]);
        int s = 2 * kh + kil;
#pragma unroll
        for (int dt = 0; dt < 4; ++dt) {
          bf16x8 vf = *(const bf16x8*)(Vsc + (4 * s + quad) * 512 +
                                       (dt * 16 + l16) * 8);
          oacc[0][dt] = MFMA16(vf, pf0, oacc[0][dt]);
          oacc[1][dt] = MFMA16(vf, pf1, oacc[1][dt]);
        }
      }
    }
    __builtin_amdgcn_s_barrier();
  }

#pragma unroll
  for (int nt = 0; nt < 2; ++nt) {
    float linv = 1.0f / lacc[nt][0];
    __bf16* Yr =
        Y + (((size_t)b * T + qt * 128 + wave * 32 + nt * 16 + l16) * 32 + h) * 64;
#pragma unroll
    for (int dt = 0; dt < 4; ++dt) {
      bf16x4v ov;
#pragma unroll
      for (int r = 0; r < 4; ++r) ov[r] = (__bf16)(oacc[nt][dt][r] * linv);
      *(bf16x4v*)(Yr + dt * 16 + quad * 4) = ov;
    }
  }
#undef STAGE_TILE
}

// ---------------------------------------------------------------------------
extern "C" void kernel_launch(void* const* d_in, const int* in_sizes, int n_in,
                              void* d_out, int out_size, void* d_ws,
                              size_t ws_size, hipStream_t stream) {
  const float* x = (const float*)d_in[0];
  const float* Wq = (const float*)d_in[1];
  const float* Wk = (const float*)d_in[2];
  const float* Wv = (const float*)d_in[3];
  const float* Wo = (const float*)d_in[4];
  float* out = (float*)d_out;

  char* ws = (char*)d_ws;
  __bf16* xb = (__bf16*)(ws);                         // 16.8MB; later y
  __bf16* W1T = (__bf16*)(ws + 16777216);             // 12.6MB
  __bf16* WoT = (__bf16*)(ws + 16777216 + 12582912);  // 8.4MB
  char* d4 = ws + 16777216 + 12582912 + 8388608;
  __bf16* Qr = (__bf16*)(d4);                   // 16.8MB
  __bf16* Kr = (__bf16*)(d4 + 16777216);        // 4.2MB
  __bf16* VT = (__bf16*)(d4 + 16777216 + 4194304);
  float* bias2 = (float*)(d4 + 16777216 + 8388608);
  __bf16* y = xb;  // xb dead after gemm_qkv

  prep_kernel<<<dim3(32, 112), 256, 0, stream>>>(x, Wq, Wk, Wv, Wo, xb, W1T,
                                                 WoT);
  gemm_qkv<<<dim3(24, 32), 256, 0, stream>>>(xb, W1T, Qr, Kr, VT, bias2);
  attn_kernel<<<dim3(32, 8, 4), 256, 0, stream>>>(Qr, Kr, VT, bias2, y);
  gemm_bt<0><<<dim3(16, 32), 256, 0, stream>>>(y, WoT, out, 4096, 2048, 2048);
}